// Round 19
// baseline (211.621 us; speedup 1.0000x reference)
//
#include <hip/hip_runtime.h>

#define NBATCH 16
#define MAXB 256
#define BS 16
#define HQ 32
#define HKV 8
#define G 4
#define HD 128
#define SCALE 0.08838834764831845f
#define NEGF -1.0e30f   // running-max init
#define NEGI -2.0e30f   // invalid-position score: exp(NEGI - m) == 0 for any m >= NEGF
#define RESCALE_THR 8.0f

// native clang vector for nontemporal builtins (float4 is a HIP class type,
// which __builtin_nontemporal_load rejects — r15 compile failure)
typedef float f32x4 __attribute__((ext_vector_type(4)));

__device__ __forceinline__ float4 nt_load4(const float* p) {
  const f32x4 v = __builtin_nontemporal_load((const f32x4*)p);
  return make_float4(v.x, v.y, v.z, v.w);
}

__device__ __forceinline__ float dot8(const float4 a0, const float4 a1,
                                      const float4 b0, const float4 b1) {
  return a0.x*b0.x + a0.y*b0.y + a0.z*b0.z + a0.w*b0.w +
         a1.x*b1.x + a1.y*b1.y + a1.z*b1.z + a1.w*b1.w;
}

// 16-lane DPP row reduction — pure VALU (DS-pipe shuffles were the r1-r4 limit)
template<int CTL>
__device__ __forceinline__ float dpp_row_add(float v) {
  const int s = __builtin_amdgcn_update_dpp(0, __float_as_int(v), CTL, 0xF, 0xF, true);
  return v + __int_as_float(s);
}
__device__ __forceinline__ float row_reduce_add(float v) {
  v = dpp_row_add<0x128>(v);  // row_ror:8
  v = dpp_row_add<0x124>(v);  // row_ror:4
  v = dpp_row_add<0x122>(v);  // row_ror:2
  v = dpp_row_add<0x121>(v);  // row_ror:1
  return v;                   // all 16 lanes of the row hold the sum
}

// Final quadrant test: NT loads x HIGH OCCUPANCY. r16 (95.2us) = NT + 4-group
// rotation (156 VGPR, 3 blk/CU); r18 showed deeper (8-group, 2 blk/CU) loses;
// r17 showed finer splits lose. This round: 2-group rotation (32 staging
// VGPRs, ~120 live) + __launch_bounds__(256,4) -> 4 blk/CU, 16 waves/CU.
// Tests whether the post-NT limiter is TLP/issue (win) or in-flight bytes
// (lose). Locked-in: NT K/V loads (r16, L2 thrash bypass); nsplit=32 (r17);
// separate reduce kernel (r12/r13: fusion poisons regalloc); reg staging
// (r8/r11: LDS +45us); co-location immaterial (r14).
__global__ __launch_bounds__(256, 4) void pa_split(
    const float* __restrict__ q,
    const float* __restrict__ knew,
    const float* __restrict__ vnew,
    const float* __restrict__ k_cache,
    const float* __restrict__ v_cache,
    const int* __restrict__ block_tables,
    const int* __restrict__ seq_lens,
    float* __restrict__ part_ml,   // [B][HKV][P][G][2]
    float* __restrict__ part_acc,  // [B][HKV][P][G][HD]
    int nsplit)
{
  const int hg    = blockIdx.x & 1;
  const int b     = (blockIdx.x >> 1) % NBATCH;    // batch-minor: balance
  const int split = blockIdx.x / (2 * NBATCH);
  const int h     = hg * 4 + (threadIdx.x >> 6);
  const int lane  = threadIdx.x & 63;
  const int tg    = lane >> 4;
  const int tl    = lane & 15;

  const int seq_len = seq_lens[b];
  int per = (seq_len + nsplit - 1) / nsplit;
  per = (per + 15) & ~15;                          // page-align chunks
  const int s0 = split * per;
  const int s1 = min(seq_len, s0 + per);
  const int last = seq_len - 1;
  const size_t pidx = (size_t)(b*HKV + h)*nsplit + split;

  if (s0 >= seq_len) {
    // inactive split: write a neutral partial (d_ws is not re-poisoned)
    if (tg == 0) {
      if (tl == 0) {
#pragma unroll
        for (int j = 0; j < G; ++j) {
          part_ml[(pidx*G + j)*2 + 0] = NEGF;
          part_ml[(pidx*G + j)*2 + 1] = 0.f;
        }
      }
      const float4 z = make_float4(0.f,0.f,0.f,0.f);
#pragma unroll
      for (int j = 0; j < G; ++j) {
        *(float4*)(part_acc + (pidx*G + j)*HD + tl*4)      = z;
        *(float4*)(part_acc + (pidx*G + j)*HD + 64 + tl*4) = z;
      }
    }
    return;
  }

  // q fragments, chunked dim map: lane owns dims {tl*4..+3, 64+tl*4..+3}
  float4 q0[G], q1[G];
#pragma unroll
  for (int j = 0; j < G; ++j) {
    const float* qp = q + (size_t)(b*HQ + h*G + j)*HD;
    q0[j] = *(const float4*)(qp + tl*4);
    q1[j] = *(const float4*)(qp + 64 + tl*4);
  }

  float m[G], l[G];
  float4 a0[G], a1[G];
#pragma unroll
  for (int j = 0; j < G; ++j) {
    m[j] = NEGF; l[j] = 0.f;
    a0[j] = make_float4(0.f,0.f,0.f,0.f);
    a1[j] = make_float4(0.f,0.f,0.f,0.f);
  }

  const float* knp = knew + (size_t)(b*HKV + h)*HD;
  const float* vnp = vnew + (size_t)(b*HKV + h)*HD;
  const int btbase = b * MAXB;

  // load one 4-position group (positions pos+tg of block blk) — NT loads
  auto loadG = [&](float4 (&kr)[2], float4 (&vr)[2], const int blk, const int pos) {
    const int s = pos + tg;
    const float* kp = k_cache + ((size_t)blk*BS + (s & 15))*(HKV*HD) + (size_t)h*HD;
    const float* vp = v_cache + ((size_t)blk*BS + (s & 15))*(HKV*HD) + (size_t)h*HD;
    if (s == last) { kp = knp; vp = vnp; }  // token written this step -> k/v inputs
    kr[0] = nt_load4(kp + tl*4);
    kr[1] = nt_load4(kp + 64 + tl*4);
    vr[0] = nt_load4(vp + tl*4);
    vr[1] = nt_load4(vp + 64 + tl*4);
  };

  auto computeG = [&](const float4 (&kr)[2], const float4 (&vr)[2], const int pos) {
    const bool valid = (pos + tg) < s1;
    float sc[G];
#pragma unroll
    for (int j = 0; j < G; ++j) {
      float p = dot8(q0[j], q1[j], kr[0], kr[1]);
      p = row_reduce_add(p);                  // VALU-only 16-lane reduce
      sc[j] = valid ? p * SCALE : NEGI;
    }
    bool need = false;
#pragma unroll
    for (int j = 0; j < G; ++j) need = need || (sc[j] > m[j] + RESCALE_THR);
    if (__any(need)) {
#pragma unroll
      for (int j = 0; j < G; ++j) {
        const float mn = fmaxf(m[j], sc[j]);
        const float f  = __expf(m[j] - mn);
        l[j] *= f;
        a0[j].x *= f; a0[j].y *= f; a0[j].z *= f; a0[j].w *= f;
        a1[j].x *= f; a1[j].y *= f; a1[j].z *= f; a1[j].w *= f;
        m[j] = mn;
      }
    }
#pragma unroll
    for (int j = 0; j < G; ++j) {
      const float pp = __expf(sc[j] - m[j]);  // bounded by e^THR; 0 for invalid
      l[j] += pp;
      a0[j].x += pp*vr[0].x; a0[j].y += pp*vr[0].y;
      a0[j].z += pp*vr[0].z; a0[j].w += pp*vr[0].w;
      a1[j].x += pp*vr[1].x; a1[j].y += pp*vr[1].y;
      a1[j].z += pp*vr[1].z; a1[j].w += pp*vr[1].w;
    }
  };

  // ---- 2-group rotation: compute(g) || load(g+2) ----
  {
    const int npos   = s1 - s0;
    const int npages = (npos + 15) >> 4;
    const int pg0    = s0 >> 4;

    float4 kA[2], vA[2], kB[2], vB[2];

    int blk     = block_tables[btbase + pg0];
    int blkNext = block_tables[btbase + pg0 + ((npages > 1) ? 1 : 0)];

    loadG(kA, vA, blk, s0);
    loadG(kB, vB, blk, s0 + 4);

    for (int p = 0; p < npages; ++p) {
      const int base  = s0 + p*16;
      const bool more = (p + 1 < npages);
      const int blkL  = blkNext;
      const int nbase = base + 16;
      const int pnn   = (p + 2 < npages) ? (p + 2) : (npages - 1);
      const int blkNN = block_tables[btbase + pg0 + pnn];

      computeG(kA, vA, base);      loadG(kA, vA, blk, base + 8);
      computeG(kB, vB, base + 4);  loadG(kB, vB, blk, base + 12);
      computeG(kA, vA, base + 8);  if (more) loadG(kA, vA, blkL, nbase);
      computeG(kB, vB, base + 12); if (more) loadG(kB, vB, blkL, nbase + 4);

      blk = blkL;
      blkNext = blkNN;
    }
  }

  // ---- combine the 4 tg partials (butterfly xor 16, 32) ----
#pragma unroll
  for (int mask = 16; mask <= 32; mask <<= 1) {
#pragma unroll
    for (int j = 0; j < G; ++j) {
      const float mo = __shfl_xor(m[j], mask, 64);
      const float lo = __shfl_xor(l[j], mask, 64);
      const float mn = fmaxf(m[j], mo);
      const float f0 = __expf(m[j] - mn);
      const float f1 = __expf(mo  - mn);
      l[j] = l[j]*f0 + lo*f1;
      float t;
      t = __shfl_xor(a0[j].x, mask, 64); a0[j].x = a0[j].x*f0 + t*f1;
      t = __shfl_xor(a0[j].y, mask, 64); a0[j].y = a0[j].y*f0 + t*f1;
      t = __shfl_xor(a0[j].z, mask, 64); a0[j].z = a0[j].z*f0 + t*f1;
      t = __shfl_xor(a0[j].w, mask, 64); a0[j].w = a0[j].w*f0 + t*f1;
      t = __shfl_xor(a1[j].x, mask, 64); a1[j].x = a1[j].x*f0 + t*f1;
      t = __shfl_xor(a1[j].y, mask, 64); a1[j].y = a1[j].y*f0 + t*f1;
      t = __shfl_xor(a1[j].z, mask, 64); a1[j].z = a1[j].z*f0 + t*f1;
      t = __shfl_xor(a1[j].w, mask, 64); a1[j].w = a1[j].w*f0 + t*f1;
      m[j] = mn;
    }
  }

  if (tg == 0) {
    if (tl == 0) {
#pragma unroll
      for (int j = 0; j < G; ++j) {
        part_ml[(pidx*G + j)*2 + 0] = m[j];
        part_ml[(pidx*G + j)*2 + 1] = l[j];
      }
    }
#pragma unroll
    for (int j = 0; j < G; ++j) {
      *(float4*)(part_acc + (pidx*G + j)*HD + tl*4)      = a0[j];
      *(float4*)(part_acc + (pidx*G + j)*HD + 64 + tl*4) = a1[j];
    }
  }
}

// Reduce: one block per (b, q-head), 128 threads (one per dim).
__global__ __launch_bounds__(128) void pa_reduce(
    const float* __restrict__ part_ml,
    const float* __restrict__ part_acc,
    float* __restrict__ out,
    int P)
{
  const int qh = blockIdx.x % HQ;
  const int b  = blockIdx.x / HQ;
  const int h  = qh >> 2;
  const int j  = qh & 3;
  const int d  = threadIdx.x;

  const size_t base = (size_t)(b*HKV + h) * P;
  float mg = NEGF;
  for (int p = 0; p < P; ++p)
    mg = fmaxf(mg, part_ml[((base + p)*G + j)*2 + 0]);

  float lsum = 0.f, asum = 0.f;
  for (int p = 0; p < P; ++p) {
    const float mm = part_ml[((base + p)*G + j)*2 + 0];
    const float ll = part_ml[((base + p)*G + j)*2 + 1];
    const float f  = __expf(mm - mg);   // inactive partial: ll==0, acc==0
    lsum += f * ll;
    asum += f * part_acc[((base + p)*G + j)*HD + d];
  }
  out[(size_t)(b*HQ + qh)*HD + d] = asum / lsum;
}

extern "C" void kernel_launch(void* const* d_in, const int* in_sizes, int n_in,
                              void* d_out, int out_size, void* d_ws, size_t ws_size,
                              hipStream_t stream) {
  const float* q  = (const float*)d_in[0];
  const float* k  = (const float*)d_in[1];
  const float* v  = (const float*)d_in[2];
  const float* kc = (const float*)d_in[3];
  const float* vc = (const float*)d_in[4];
  // d_in[5] = slot_mapping (unused: it addresses logical position seq_len-1)
  const int* bt = (const int*)d_in[6];
  const int* sl = (const int*)d_in[7];
  // d_in[8] = query_lens (all 1), d_in[9] = is_prefill (False) — unused

  int nsplit = 32;
  for (;;) {
    const size_t need = (size_t)NBATCH * HKV * nsplit * G * (2 + HD) * sizeof(float);
    if (need <= ws_size || nsplit == 1) break;
    nsplit >>= 1;
  }
  float* part_ml  = (float*)d_ws;
  float* part_acc = part_ml + (size_t)NBATCH * HKV * nsplit * G * 2;

  hipLaunchKernelGGL(pa_split, dim3(NBATCH * nsplit * 2), dim3(256), 0, stream,
                     q, k, v, kc, vc, bt, sl, part_ml, part_acc, nsplit);
  hipLaunchKernelGGL(pa_reduce, dim3(NBATCH * HQ), dim3(128), 0, stream,
                     part_ml, part_acc, (float*)d_out, nsplit);
}

// Round 20
// 95.184 us; speedup vs baseline: 2.2233x; 2.2233x over previous
//
#include <hip/hip_runtime.h>

#define NBATCH 16
#define MAXB 256
#define BS 16
#define HQ 32
#define HKV 8
#define G 4
#define HD 128
#define SCALE 0.08838834764831845f
#define NEGF -1.0e30f   // running-max init
#define NEGI -2.0e30f   // invalid-position score: exp(NEGI - m) == 0 for any m >= NEGF
#define RESCALE_THR 8.0f

// native clang vector for nontemporal builtins (float4 is a HIP class type,
// which __builtin_nontemporal_load rejects — r15 compile failure)
typedef float f32x4 __attribute__((ext_vector_type(4)));

__device__ __forceinline__ float4 nt_load4(const float* p) {
  const f32x4 v = __builtin_nontemporal_load((const f32x4*)p);
  return make_float4(v.x, v.y, v.z, v.w);
}

__device__ __forceinline__ float dot8(const float4 a0, const float4 a1,
                                      const float4 b0, const float4 b1) {
  return a0.x*b0.x + a0.y*b0.y + a0.z*b0.z + a0.w*b0.w +
         a1.x*b1.x + a1.y*b1.y + a1.z*b1.z + a1.w*b1.w;
}

// 16-lane DPP row reduction — pure VALU (DS-pipe shuffles were the r1-r4 limit)
template<int CTL>
__device__ __forceinline__ float dpp_row_add(float v) {
  const int s = __builtin_amdgcn_update_dpp(0, __float_as_int(v), CTL, 0xF, 0xF, true);
  return v + __int_as_float(s);
}
__device__ __forceinline__ float row_reduce_add(float v) {
  v = dpp_row_add<0x128>(v);  // row_ror:8
  v = dpp_row_add<0x124>(v);  // row_ror:4
  v = dpp_row_add<0x122>(v);  // row_ror:2
  v = dpp_row_add<0x121>(v);  // row_ror:1
  return v;                   // all 16 lanes of the row hold the sum
}

// FINAL (r16 winner, 95.2us, restored verbatim after r17-r19 regressions):
// r9 rotating 4-buffer register pipeline + NONTEMPORAL K/V loads (bypass the
// L2 that 400MB of read-once K/V purely thrashed: 105.5 -> 95.2us), nsplit=32,
// separate reduce kernel.
// Measured design space: deeper pipeline (r18, 2 blk/CU): -12%; finer splits
// (r17): -16%; high-occupancy cap (r19): spills, -2.2x; LDS staging (r8/r11):
// -45%; head co-location (r7/r14): neutral/worse; fused reduce (r12/r13):
// regalloc collapse, -3x. Three distinct max-MLP structures all saturate at
// ~4.2-4.7 TB/s effective for this 512B-granule gather (vs 6.9 TB/s
// contiguous fill) -> practical pattern ceiling.
__global__ __launch_bounds__(256) void pa_split(
    const float* __restrict__ q,
    const float* __restrict__ knew,
    const float* __restrict__ vnew,
    const float* __restrict__ k_cache,
    const float* __restrict__ v_cache,
    const int* __restrict__ block_tables,
    const int* __restrict__ seq_lens,
    float* __restrict__ part_ml,   // [B][HKV][P][G][2]
    float* __restrict__ part_acc,  // [B][HKV][P][G][HD]
    int nsplit)
{
  const int hg    = blockIdx.x & 1;
  const int b     = (blockIdx.x >> 1) % NBATCH;    // batch-minor: balance
  const int split = blockIdx.x / (2 * NBATCH);
  const int h     = hg * 4 + (threadIdx.x >> 6);
  const int lane  = threadIdx.x & 63;
  const int tg    = lane >> 4;
  const int tl    = lane & 15;

  const int seq_len = seq_lens[b];
  int per = (seq_len + nsplit - 1) / nsplit;
  per = (per + 15) & ~15;                          // page-align chunks
  const int s0 = split * per;
  const int s1 = min(seq_len, s0 + per);
  const int last = seq_len - 1;
  const size_t pidx = (size_t)(b*HKV + h)*nsplit + split;

  if (s0 >= seq_len) {
    // inactive split: write a neutral partial (d_ws is not re-poisoned)
    if (tg == 0) {
      if (tl == 0) {
#pragma unroll
        for (int j = 0; j < G; ++j) {
          part_ml[(pidx*G + j)*2 + 0] = NEGF;
          part_ml[(pidx*G + j)*2 + 1] = 0.f;
        }
      }
      const float4 z = make_float4(0.f,0.f,0.f,0.f);
#pragma unroll
      for (int j = 0; j < G; ++j) {
        *(float4*)(part_acc + (pidx*G + j)*HD + tl*4)      = z;
        *(float4*)(part_acc + (pidx*G + j)*HD + 64 + tl*4) = z;
      }
    }
    return;
  }

  // q fragments, chunked dim map: lane owns dims {tl*4..+3, 64+tl*4..+3}
  float4 q0[G], q1[G];
#pragma unroll
  for (int j = 0; j < G; ++j) {
    const float* qp = q + (size_t)(b*HQ + h*G + j)*HD;
    q0[j] = *(const float4*)(qp + tl*4);
    q1[j] = *(const float4*)(qp + 64 + tl*4);
  }

  float m[G], l[G];
  float4 a0[G], a1[G];
#pragma unroll
  for (int j = 0; j < G; ++j) {
    m[j] = NEGF; l[j] = 0.f;
    a0[j] = make_float4(0.f,0.f,0.f,0.f);
    a1[j] = make_float4(0.f,0.f,0.f,0.f);
  }

  const float* knp = knew + (size_t)(b*HKV + h)*HD;
  const float* vnp = vnew + (size_t)(b*HKV + h)*HD;
  const int btbase = b * MAXB;

  // load one 4-position group (positions pos+tg of block blk) — NT loads
  auto loadG = [&](float4 (&kr)[2], float4 (&vr)[2], const int blk, const int pos) {
    const int s = pos + tg;
    const float* kp = k_cache + ((size_t)blk*BS + (s & 15))*(HKV*HD) + (size_t)h*HD;
    const float* vp = v_cache + ((size_t)blk*BS + (s & 15))*(HKV*HD) + (size_t)h*HD;
    if (s == last) { kp = knp; vp = vnp; }  // token written this step -> k/v inputs
    kr[0] = nt_load4(kp + tl*4);
    kr[1] = nt_load4(kp + 64 + tl*4);
    vr[0] = nt_load4(vp + tl*4);
    vr[1] = nt_load4(vp + 64 + tl*4);
  };

  auto computeG = [&](const float4 (&kr)[2], const float4 (&vr)[2], const int pos) {
    const bool valid = (pos + tg) < s1;
    float sc[G];
#pragma unroll
    for (int j = 0; j < G; ++j) {
      float p = dot8(q0[j], q1[j], kr[0], kr[1]);
      p = row_reduce_add(p);                  // VALU-only 16-lane reduce
      sc[j] = valid ? p * SCALE : NEGI;
    }
    bool need = false;
#pragma unroll
    for (int j = 0; j < G; ++j) need = need || (sc[j] > m[j] + RESCALE_THR);
    if (__any(need)) {
#pragma unroll
      for (int j = 0; j < G; ++j) {
        const float mn = fmaxf(m[j], sc[j]);
        const float f  = __expf(m[j] - mn);
        l[j] *= f;
        a0[j].x *= f; a0[j].y *= f; a0[j].z *= f; a0[j].w *= f;
        a1[j].x *= f; a1[j].y *= f; a1[j].z *= f; a1[j].w *= f;
        m[j] = mn;
      }
    }
#pragma unroll
    for (int j = 0; j < G; ++j) {
      const float pp = __expf(sc[j] - m[j]);  // bounded by e^THR; 0 for invalid
      l[j] += pp;
      a0[j].x += pp*vr[0].x; a0[j].y += pp*vr[0].y;
      a0[j].z += pp*vr[0].z; a0[j].w += pp*vr[0].w;
      a1[j].x += pp*vr[1].x; a1[j].y += pp*vr[1].y;
      a1[j].z += pp*vr[1].z; a1[j].w += pp*vr[1].w;
    }
  };

  // ---- rotating 4-buffer pipeline: compute(g) || load(g+4)  ----
  {
    const int npos   = s1 - s0;
    const int npages = (npos + 15) >> 4;
    const int pg0    = s0 >> 4;

    float4 kA[2], vA[2], kB[2], vB[2], kC[2], vC[2], kD[2], vD[2];

    int blkCur  = block_tables[btbase + pg0];
    int blkNext = block_tables[btbase + pg0 + ((npages > 1) ? 1 : 0)];

    loadG(kA, vA, blkCur, s0);
    loadG(kB, vB, blkCur, s0 + 4);
    loadG(kC, vC, blkCur, s0 + 8);
    loadG(kD, vD, blkCur, s0 + 12);

    for (int p = 0; p < npages; ++p) {
      const int base  = s0 + p*16;
      const bool more = (p + 1 < npages);
      const int blkL  = blkNext;
      const int lbase = base + 16;
      const int pnn   = (p + 2 < npages) ? (p + 2) : (npages - 1);
      const int blkNN = block_tables[btbase + pg0 + pnn];

      computeG(kA, vA, base);
      if (more) loadG(kA, vA, blkL, lbase);
      computeG(kB, vB, base + 4);
      if (more) loadG(kB, vB, blkL, lbase + 4);
      computeG(kC, vC, base + 8);
      if (more) loadG(kC, vC, blkL, lbase + 8);
      computeG(kD, vD, base + 12);
      if (more) loadG(kD, vD, blkL, lbase + 12);

      blkNext = blkNN;
    }
  }

  // ---- combine the 4 tg partials (butterfly xor 16, 32) ----
#pragma unroll
  for (int mask = 16; mask <= 32; mask <<= 1) {
#pragma unroll
    for (int j = 0; j < G; ++j) {
      const float mo = __shfl_xor(m[j], mask, 64);
      const float lo = __shfl_xor(l[j], mask, 64);
      const float mn = fmaxf(m[j], mo);
      const float f0 = __expf(m[j] - mn);
      const float f1 = __expf(mo  - mn);
      l[j] = l[j]*f0 + lo*f1;
      float t;
      t = __shfl_xor(a0[j].x, mask, 64); a0[j].x = a0[j].x*f0 + t*f1;
      t = __shfl_xor(a0[j].y, mask, 64); a0[j].y = a0[j].y*f0 + t*f1;
      t = __shfl_xor(a0[j].z, mask, 64); a0[j].z = a0[j].z*f0 + t*f1;
      t = __shfl_xor(a0[j].w, mask, 64); a0[j].w = a0[j].w*f0 + t*f1;
      t = __shfl_xor(a1[j].x, mask, 64); a1[j].x = a1[j].x*f0 + t*f1;
      t = __shfl_xor(a1[j].y, mask, 64); a1[j].y = a1[j].y*f0 + t*f1;
      t = __shfl_xor(a1[j].z, mask, 64); a1[j].z = a1[j].z*f0 + t*f1;
      t = __shfl_xor(a1[j].w, mask, 64); a1[j].w = a1[j].w*f0 + t*f1;
      m[j] = mn;
    }
  }

  if (tg == 0) {
    if (tl == 0) {
#pragma unroll
      for (int j = 0; j < G; ++j) {
        part_ml[(pidx*G + j)*2 + 0] = m[j];
        part_ml[(pidx*G + j)*2 + 1] = l[j];
      }
    }
#pragma unroll
    for (int j = 0; j < G; ++j) {
      *(float4*)(part_acc + (pidx*G + j)*HD + tl*4)      = a0[j];
      *(float4*)(part_acc + (pidx*G + j)*HD + 64 + tl*4) = a1[j];
    }
  }
}

// Reduce: one block per (b, q-head), 128 threads (one per dim).
__global__ __launch_bounds__(128) void pa_reduce(
    const float* __restrict__ part_ml,
    const float* __restrict__ part_acc,
    float* __restrict__ out,
    int P)
{
  const int qh = blockIdx.x % HQ;
  const int b  = blockIdx.x / HQ;
  const int h  = qh >> 2;
  const int j  = qh & 3;
  const int d  = threadIdx.x;

  const size_t base = (size_t)(b*HKV + h) * P;
  float mg = NEGF;
  for (int p = 0; p < P; ++p)
    mg = fmaxf(mg, part_ml[((base + p)*G + j)*2 + 0]);

  float lsum = 0.f, asum = 0.f;
  for (int p = 0; p < P; ++p) {
    const float mm = part_ml[((base + p)*G + j)*2 + 0];
    const float ll = part_ml[((base + p)*G + j)*2 + 1];
    const float f  = __expf(mm - mg);   // inactive partial: ll==0, acc==0
    lsum += f * ll;
    asum += f * part_acc[((base + p)*G + j)*HD + d];
  }
  out[(size_t)(b*HQ + qh)*HD + d] = asum / lsum;
}

extern "C" void kernel_launch(void* const* d_in, const int* in_sizes, int n_in,
                              void* d_out, int out_size, void* d_ws, size_t ws_size,
                              hipStream_t stream) {
  const float* q  = (const float*)d_in[0];
  const float* k  = (const float*)d_in[1];
  const float* v  = (const float*)d_in[2];
  const float* kc = (const float*)d_in[3];
  const float* vc = (const float*)d_in[4];
  // d_in[5] = slot_mapping (unused: it addresses logical position seq_len-1)
  const int* bt = (const int*)d_in[6];
  const int* sl = (const int*)d_in[7];
  // d_in[8] = query_lens (all 1), d_in[9] = is_prefill (False) — unused

  int nsplit = 32;
  for (;;) {
    const size_t need = (size_t)NBATCH * HKV * nsplit * G * (2 + HD) * sizeof(float);
    if (need <= ws_size || nsplit == 1) break;
    nsplit >>= 1;
  }
  float* part_ml  = (float*)d_ws;
  float* part_acc = part_ml + (size_t)NBATCH * HKV * nsplit * G * 2;

  hipLaunchKernelGGL(pa_split, dim3(NBATCH * nsplit * 2), dim3(256), 0, stream,
                     q, k, v, kc, vc, bt, sl, part_ml, part_acc, nsplit);
  hipLaunchKernelGGL(pa_reduce, dim3(NBATCH * HQ), dim3(128), 0, stream,
                     part_ml, part_acc, (float*)d_out, nsplit);
}